// Round 5
// baseline (180.682 us; speedup 1.0000x reference)
//
#include <hip/hip_runtime.h>
#include <hip/hip_bf16.h>
#include <math.h>

typedef __bf16 bf16_t;
typedef __bf16 bf16x8 __attribute__((ext_vector_type(8)));
typedef __bf16 bf16x4 __attribute__((ext_vector_type(4)));
typedef __bf16 bf16x2 __attribute__((ext_vector_type(2)));
typedef float f32x4 __attribute__((ext_vector_type(4)));
typedef unsigned u32x4 __attribute__((ext_vector_type(4)));

// scale 1/sqrt(1024) folded with log2(e), plus half-ulp rounding bias
// (x * 2^0.0028169 = x * (1+2^-9)) so perm-truncation rounds on average.
#define SCALE_L2E 0.045084234f
#define ROUND_B 0.0028169f

#define MFMA16(a, b, c) __builtin_amdgcn_mfma_f32_16x16x32_bf16(a, b, c, 0, 0, 0)

// pack two f32 into bf16x2 (truncate): dst = (hi16(b) << 16) | hi16(a)
__device__ __forceinline__ unsigned pack2(float a, float b) {
  return __builtin_amdgcn_perm(__builtin_bit_cast(unsigned, b),
                               __builtin_bit_cast(unsigned, a), 0x07060302u);
}

// ---------------------------------------------------------------------------
// fused f32 -> bf16 convert of three buffers (x, w_qkv, w_o), 8 elems/thread
// ---------------------------------------------------------------------------
__global__ void convert3_f32_bf16(const float* __restrict__ a, int na,
                                  const float* __restrict__ b, int nb,
                                  const float* __restrict__ c, int nc,
                                  bf16_t* __restrict__ oa, bf16_t* __restrict__ ob,
                                  bf16_t* __restrict__ oc) {
  int i = (blockIdx.x * blockDim.x + threadIdx.x) * 8;
  const float* src;
  bf16_t* dst;
  int off;
  if (i < na) { src = a; dst = oa; off = i; }
  else if (i < na + nb) { src = b; dst = ob; off = i - na; }
  else if (i < na + nb + nc) { src = c; dst = oc; off = i - na - nb; }
  else return;
  float4 u = *(const float4*)&src[off];
  float4 v = *(const float4*)&src[off + 4];
  bf16x8 w = {(bf16_t)u.x, (bf16_t)u.y, (bf16_t)u.z, (bf16_t)u.w,
              (bf16_t)v.x, (bf16_t)v.y, (bf16_t)v.z, (bf16_t)v.w};
  *(bf16x8*)&dst[off] = w;
}

#define GLOBAL_AS __attribute__((address_space(1)))
#define LDS_AS __attribute__((address_space(3)))
__device__ __forceinline__ void g2l16(const void* g, void* l) {
  __builtin_amdgcn_global_load_lds((const GLOBAL_AS void*)g, (LDS_AS void*)l,
                                   16, 0, 0);
}

// ---------------------------------------------------------------------------
// m97-style BT-GEMM, bf16 in: C[m,n] = sum_k A[m,k]*B[n,k] + bias[n]
// R4->R5: GEMM2 now uses BN=128 (this template's BN=128 path is the one that
// ran as GEMM1 in R0/R1 and passed refcheck) — 2x MFMA per staging event,
// halves A re-fetch (N/BN strips 16 -> 8).
// ---------------------------------------------------------------------------
template <typename TC, int BN>
__launch_bounds__(256)
__global__ void gemm_bt_bias(const bf16_t* __restrict__ A,
                             const bf16_t* __restrict__ B,
                             const float* __restrict__ bias,
                             TC* __restrict__ C,
                             int M, int N, int K) {
  constexpr int NT = BN / 32;  // n-frags per wave
  __shared__ bf16_t As[128 * 32];
  __shared__ bf16_t Bs[BN * 32];

  const int t = threadIdx.x;
  const int wave = t >> 6, lane = t & 63, quad = lane >> 4, ln = lane & 15;
  const int wm = (wave >> 1) * 64, wn = (wave & 1) * (BN / 2);
  const int m0 = blockIdx.y * 128, n0 = blockIdx.x * BN;

  const int srow = lane >> 2;
  const int schunk = ((lane & 3) ^ ((lane >> 3) & 3)) * 8;
  const bf16_t* gA0 = &A[(size_t)(m0 + wave * 32 + srow) * K + schunk];
  const bf16_t* gA1 = gA0 + (size_t)16 * K;
  bf16_t* lA0 = &As[(wave * 32) * 32];
  bf16_t* lA1 = &As[(wave * 32 + 16) * 32];
  const bf16_t* gB0 = &B[(size_t)(n0 + (BN == 128 ? wave * 32 : wave * 16) + srow) * K + schunk];
  const bf16_t* gB1 = gB0 + (size_t)16 * K;
  bf16_t* lB0 = &Bs[((BN == 128 ? wave * 32 : wave * 16)) * 32];
  bf16_t* lB1 = &Bs[(wave * 32 + 16) * 32];

  const int cslot = (quad ^ ((ln >> 1) & 3)) * 8;

  f32x4 acc[4][NT];
  for (int i = 0; i < 4; i++)
    for (int j = 0; j < NT; j++) acc[i][j] = (f32x4){0.f, 0.f, 0.f, 0.f};

  for (int k0 = 0; k0 < K; k0 += 32) {
    __syncthreads();
    g2l16(gA0 + k0, lA0);
    g2l16(gA1 + k0, lA1);
    g2l16(gB0 + k0, lB0);
    if (BN == 128) g2l16(gB1 + k0, lB1);
    __syncthreads();

    bf16x8 af[4], bfr[NT];
    for (int mt = 0; mt < 4; mt++)
      af[mt] = *(const bf16x8*)&As[(wm + mt * 16 + ln) * 32 + cslot];
    for (int nt = 0; nt < NT; nt++)
      bfr[nt] = *(const bf16x8*)&Bs[(wn + nt * 16 + ln) * 32 + cslot];
    for (int mt = 0; mt < 4; mt++)
      for (int nt = 0; nt < NT; nt++)
        acc[mt][nt] = MFMA16(af[mt], bfr[nt], acc[mt][nt]);
  }

  for (int nt = 0; nt < NT; nt++) {
    int col = n0 + wn + nt * 16 + ln;
    float bv = bias[col];
    for (int mt = 0; mt < 4; mt++) {
      int row = m0 + wm + mt * 16 + quad * 4;
      for (int r = 0; r < 4; r++)
        C[(size_t)(row + r) * N + col] = (TC)(acc[mt][nt][r] + bv);
    }
  }
}

// ---------------------------------------------------------------------------
// 256x256 8-phase BT-GEMM (T2 swizzle + T3/T4 counted vmcnt + T5 setprio).
// 8 waves (2M x 4N), BK=64, 128 KiB LDS double-buffer. Per K-tile: 4 phases,
// each {ds_read frags | stage one 16KB chunk | barrier | lgkmcnt(0) |
// setprio(1) 16xMFMA setprio(0) | barrier}; vmcnt(4) once per tile.
// Chunk schedule (tile t phases): P1: A_1(t+1)  P2: B_1(t+1)
//                                 P3: A_0(t+2)  P4: B_0(t+2)
// Release proof: A_0 (rows 0-127) last read P2 (mh0); B_0 last read P3 (nh0);
// A_1/B_1 of buf[(t+1)&1] last read P3/P4 of tile t-1. All stage targets are
// disjoint from same-phase reads; vmcnt(4) leaves exactly the 2 newest chunks
// (tile t+2's A_0,B_0) in flight, so tile t+1 is fully landed at its P1.
// Wave ownership interleaved so every chunk is a contiguous 128-row block:
//   wm owns rows {wm*64+[0,64)} u {128+wm*64+[0,64)}
//   wn owns cols {wn*32+[0,32)} u {128+wn*32+[0,32)}
// LDS XOR swizzle: chunk' = chunk ^ (row&7)  (2-way ds_read_b128 -> free);
// global source pre-applies the same involution (rule 21).
// ---------------------------------------------------------------------------
__launch_bounds__(512, 2)
__global__ void gemm256_bt_bias(const bf16_t* __restrict__ A,
                                const bf16_t* __restrict__ B,
                                const float* __restrict__ bias,
                                bf16_t* __restrict__ C,
                                int M, int N, int K) {
  __shared__ __align__(16) bf16_t Ab[2][256 * 64];
  __shared__ __align__(16) bf16_t Bb[2][256 * 64];

  const int tid = threadIdx.x;
  const int wave = tid >> 6, lane = tid & 63, quad = lane >> 4, ln = lane & 15;
  const int wm = wave >> 2, wn = wave & 3;  // 2M x 4N
  const int m0 = blockIdx.y * 256, n0 = blockIdx.x * 256;
  const int nt = K >> 6;

  // staging geometry: wave w stages 8 rows per load, lane l -> row +l/8,
  // stored k-chunk l&7 holds logical chunk (l&7)^(l>>3)  (row&7 == l>>3)
  const int rowoff = wave * 8 + (lane >> 3);
  const int c8 = ((lane & 7) ^ (lane >> 3)) * 8;
  const int w8row = wave * 8;
  const bf16_t* Arow0 = A + (size_t)(m0 + rowoff) * K + c8;
  const bf16_t* Brow0 = B + (size_t)(n0 + rowoff) * K + c8;

  auto stA = [&](int tl, int h) {
    const bf16_t* g = Arow0 + (size_t)(h * 128) * K + (size_t)tl * 64;
    bf16_t* l = &Ab[tl & 1][(h * 128 + w8row) * 64];
    g2l16(g, l);
    g2l16(g + (size_t)64 * K, l + 64 * 64);
  };
  auto stB = [&](int tl, int h) {
    const bf16_t* g = Brow0 + (size_t)(h * 128) * K + (size_t)tl * 64;
    bf16_t* l = &Bb[tl & 1][(h * 128 + w8row) * 64];
    g2l16(g, l);
    g2l16(g + (size_t)64 * K, l + 64 * 64);
  };

  // fragment read addressing (read-side swizzle = same involution)
  const int cswl = (quad ^ (ln & 7)) * 8;     // chunk slot bytes/2 for sk=0
  const int aBase = (wm * 64 + ln) * 64;
  const int bBase = (wn * 32 + ln) * 64;

  f32x4 acc[8][4];
#pragma unroll
  for (int i = 0; i < 8; i++)
#pragma unroll
    for (int j = 0; j < 4; j++) acc[i][j] = (f32x4){0.f, 0.f, 0.f, 0.f};

  bf16x8 af[4][2], bfr[2][2];

  auto ldA4 = [&](int buf, int mh) {
#pragma unroll
    for (int mf = 0; mf < 4; ++mf)
#pragma unroll
      for (int sk = 0; sk < 2; ++sk)
        af[mf][sk] = *(const bf16x8*)&Ab[buf][mh * 8192 + aBase + mf * 1024 +
                                             (cswl ^ (sk << 5))];
  };
  auto ldB2 = [&](int buf, int nh) {
#pragma unroll
    for (int nf = 0; nf < 2; ++nf)
#pragma unroll
      for (int sk = 0; sk < 2; ++sk)
        bfr[nf][sk] = *(const bf16x8*)&Bb[buf][nh * 8192 + bBase + nf * 1024 +
                                               (cswl ^ (sk << 5))];
  };
  auto mm8 = [&](int mh, int nh) {
#pragma unroll
    for (int mf = 0; mf < 4; ++mf)
#pragma unroll
      for (int nf = 0; nf < 2; ++nf) {
        f32x4 c = acc[mh * 4 + mf][nh * 2 + nf];
        c = MFMA16(af[mf][0], bfr[nf][0], c);
        c = MFMA16(af[mf][1], bfr[nf][1], c);
        acc[mh * 4 + mf][nh * 2 + nf] = c;
      }
  };

#define PHASE_MM(MH, NH)                             \
  __builtin_amdgcn_s_barrier();                      \
  asm volatile("s_waitcnt lgkmcnt(0)" ::: "memory"); \
  __builtin_amdgcn_s_setprio(1);                     \
  mm8(MH, NH);                                       \
  __builtin_amdgcn_s_setprio(0);

  // prologue: tile 0 fully + tile 1's A_0,B_0; allow the newest 2 chunks to
  // stay in flight.
  stA(0, 0); stB(0, 0); stA(0, 1); stB(0, 1);
  if (nt > 1) {
    stA(1, 0); stB(1, 0);
    asm volatile("s_waitcnt vmcnt(4)" ::: "memory");
  } else {
    asm volatile("s_waitcnt vmcnt(0)" ::: "memory");
  }
  __builtin_amdgcn_s_barrier();

  for (int tl = 0; tl < nt; ++tl) {
    const int buf = tl & 1;
    // P1 (mh0, nh0)
    ldA4(buf, 0);
    ldB2(buf, 0);
    if (tl + 1 < nt) stA(tl + 1, 1);
    PHASE_MM(0, 0)
    __builtin_amdgcn_s_barrier();
    // P2 (mh0, nh1)
    ldB2(buf, 1);
    if (tl + 1 < nt) stB(tl + 1, 1);
    PHASE_MM(0, 1)
    __builtin_amdgcn_s_barrier();
    // P3 (mh1, nh0)
    ldA4(buf, 1);
    ldB2(buf, 0);
    if (tl + 2 < nt) stA(tl + 2, 0);
    PHASE_MM(1, 0)
    __builtin_amdgcn_s_barrier();
    // P4 (mh1, nh1)
    ldB2(buf, 1);
    if (tl + 2 < nt) stB(tl + 2, 0);
    PHASE_MM(1, 1)
    asm volatile("s_waitcnt vmcnt(4)" ::: "memory");
    __builtin_amdgcn_s_barrier();
  }
#undef PHASE_MM

#pragma unroll
  for (int nf4 = 0; nf4 < 4; ++nf4) {
    const int col = n0 + (nf4 >> 1) * 128 + wn * 32 + (nf4 & 1) * 16 + ln;
    const float bv = bias[col];
#pragma unroll
    for (int mf8 = 0; mf8 < 8; ++mf8) {
      const int row = m0 + (mf8 >> 2) * 128 + wm * 64 + (mf8 & 3) * 16 + quad * 4;
#pragma unroll
      for (int r = 0; r < 4; ++r)
        C[(size_t)(row + r) * N + col] = (bf16_t)(acc[mf8][nf4][r] + bv);
    }
  }
}

// ---------------------------------------------------------------------------
// Causal attention: MFMA layout chaining, fused-pair K=32 PV, DOUBLE-BUFFERED
// LDS (1 barrier/iter) and PEELED causal phases (mask ops only on the 2
// diagonal iterations). Block = paired q-tiles (p, 31-p): 512 blocks, equal
// work, 2/CU co-resident. Paired = best measured (R3 175.5): each staged K/V
// tile and each kf/vf fragment serves TWO q-sets (R4 unpair was neutral —
// occupancy gain cancelled by 2x LDS-read work). Ks/Vt chunk-rotate swizzled.
// R3 XCD-locality: p in HIGH bits, bh in LOW 5 bits -> same-bh -> same XCD
// (mod 8); 4 bh x 512KB K/V = 2MB < 4MB L2/XCD. T5 setprio on MFMA clusters.
// GRID MUST BE 512 (1024 clobbers wob via phantom b=2,3 — R4 failure).
// ---------------------------------------------------------------------------
__launch_bounds__(256, 2)
__global__ void attn_kernel(const bf16_t* __restrict__ qkv,
                            bf16_t* __restrict__ out) {
  constexpr int KP = 72, VP = 72;
  constexpr int BUF = 64 * KP;  // elems per K (or V) buffer
  __shared__ __align__(16) bf16_t KsB[2 * BUF];  // [buf][k][d], swizzled
  __shared__ __align__(16) bf16_t VtB[2 * BUF];  // [buf][d][k], swizzled

  const int t = threadIdx.x;
  const int wave = t >> 6, lane = t & 63, quad = lane >> 4, ln = lane & 15;
  const int p = blockIdx.x >> 5;   // pair: q-tiles p and 31-p (0..15)
  const int bh = blockIdx.x & 31;  // 0..31; same-bh -> same XCD (mod-8)
  const int b = bh >> 4, h = bh & 15;
  const int qA = p * 64, qB = (31 - p) * 64;
  const int ntiles = 32 - p;       // A active for kt <= p; B for all
  const size_t rs = 3072;
  const size_t base = (size_t)b * 2048 * rs;

  // Q as B-operand frags: B[d=quad*8+j][q=ln] = Q[q][d]
  const size_t qoffA = base + (size_t)(qA + wave * 16 + ln) * rs + h * 64;
  const size_t qoffB = base + (size_t)(qB + wave * 16 + ln) * rs + h * 64;
  bf16x8 qfA0 = *(const bf16x8*)&qkv[qoffA + quad * 8];
  bf16x8 qfA1 = *(const bf16x8*)&qkv[qoffA + 32 + quad * 8];
  bf16x8 qfB0 = *(const bf16x8*)&qkv[qoffB + quad * 8];
  bf16x8 qfB1 = *(const bf16x8*)&qkv[qoffB + 32 + quad * 8];

  // O^T accumulators: rows d = ct*16+quad*4+r, col q = ln
  f32x4 oA[4], oB[4];
  float lAx = 0.f, lBx = 0.f;
  for (int ct = 0; ct < 4; ct++) {
    oA[ct] = (f32x4){0.f, 0.f, 0.f, 0.f};
    oB[ct] = (f32x4){0.f, 0.f, 0.f, 0.f};
  }

  // staging maps: K rows r0, r0+32 (b128); V rows 2*r0, 2*r0+1 (b32 pairs)
  const int r0 = t >> 3, c0 = (t & 7) * 8;
  const int ksA = r0 * KP + (((t & 7) + wave) & 7) * 8;  // r0>>3 == wave
  const int ksB2 = (r0 + 32) * KP + (((t & 7) + wave + 4) & 7) * 8;
  const int vkoff = ((((r0 >> 2) + (t & 7)) & 7)) * 8 + 2 * (r0 & 3);

  // running global prefetch pointers (advance by 64 rows per tile)
  const bf16_t* kpa = &qkv[base + 1024 + h * 64 + (size_t)r0 * rs + c0];
  const bf16_t* kpb = kpa + (size_t)32 * rs;
  const bf16_t* vpa = &qkv[base + 2048 + h * 64 + (size_t)(2 * r0) * rs + c0];
  const bf16_t* vpb = vpa + rs;
  const size_t tstep = (size_t)64 * rs;

  // tile 0 into regs
  bf16x8 ka = *(const bf16x8*)kpa; kpa += tstep;
  bf16x8 kb = *(const bf16x8*)kpb; kpb += tstep;
  bf16x8 va2 = *(const bf16x8*)vpa; vpa += tstep;
  bf16x8 vb2 = *(const bf16x8*)vpb; vpb += tstep;

  const int qgA = qA + wave * 16 + ln;  // lane's q (S^T column), set A
  const int qgB = qB + wave * 16 + ln;

  // ---- helpers (forceinline lambdas; bool args are literal at call sites)
  auto stage_to = [&](int buf) {
    bf16_t* KsW = &KsB[buf * BUF];
    bf16_t* VtW = &VtB[buf * BUF];
    *(bf16x8*)&KsW[ksA] = ka;
    *(bf16x8*)&KsW[ksB2] = kb;
#pragma unroll
    for (int j = 0; j < 8; j++) {
      bf16x2 w2 = {va2[j], vb2[j]};
      *(bf16x2*)&VtW[(c0 + j) * VP + vkoff] = w2;
    }
  };
  auto prefetch = [&]() {
    ka = *(const bf16x8*)kpa; kpa += tstep;
    kb = *(const bf16x8*)kpb; kpb += tstep;
    va2 = *(const bf16x8*)vpa; vpa += tstep;
    vb2 = *(const bf16x8*)vpb; vpb += tstep;
  };
  auto load_kfs = [&](const bf16_t* Ks, bf16x8* kf0s, bf16x8* kf1s) {
#pragma unroll
    for (int st = 0; st < 4; st++) {
      const int krow = st * 16 + ln;
      const int rot = 2 * st + (ln >> 3);
      kf0s[st] = *(const bf16x8*)&Ks[krow * KP + ((quad + rot) & 7) * 8];
      kf1s[st] = *(const bf16x8*)&Ks[krow * KP + ((quad + 4 + rot) & 7) * 8];
    }
  };
  auto qk_block = [&](const bf16x8* kf0s, const bf16x8* kf1s, bf16x8 q0,
                      bf16x8 q1, float& lx, bf16x8* Bp, bool masked,
                      int kbase, int qg) {
#pragma unroll
    for (int pr = 0; pr < 2; pr++) {
      u32x4 u;
#pragma unroll
      for (int sh = 0; sh < 2; sh++) {
        const int st = pr * 2 + sh;
        f32x4 s = (f32x4){0.f, 0.f, 0.f, 0.f};
        __builtin_amdgcn_s_setprio(1);
        s = MFMA16(kf0s[st], q0, s);
        s = MFMA16(kf1s[st], q1, s);
        __builtin_amdgcn_s_setprio(0);
        const int k0g = kbase + st * 16 + quad * 4;
        float pv[4];
#pragma unroll
        for (int r = 0; r < 4; r++) {
          float e = __builtin_amdgcn_exp2f(fmaf(s[r], SCALE_L2E, ROUND_B));
          if (masked && (k0g + r > qg)) e = 0.f;
          lx += e;
          pv[r] = e;
        }
        u[sh * 2] = pack2(pv[0], pv[1]);
        u[sh * 2 + 1] = pack2(pv[2], pv[3]);
      }
      Bp[pr] = __builtin_bit_cast(bf16x8, u);
    }
  };
  auto load_vfs = [&](const bf16_t* Vt, bf16x8* A8s) {
#pragma unroll
    for (int pr = 0; pr < 2; pr++) {
#pragma unroll
      for (int ct = 0; ct < 4; ct++) {
        const int dd = ct * 16 + ln;
        const int bc = (quad >> 1) + 2 * ct + (ln >> 3);
        const int cA = (4 * pr + bc) & 7;
        const int cB = (4 * pr + 2 + bc) & 7;
        bf16x4 v0 = *(const bf16x4*)&Vt[dd * VP + cA * 8 + (quad & 1) * 4];
        bf16x4 v1 = *(const bf16x4*)&Vt[dd * VP + cB * 8 + (quad & 1) * 4];
        A8s[pr * 4 + ct] = __builtin_shufflevector(v0, v1, 0, 1, 2, 3, 4, 5, 6, 7);
      }
    }
  };

  // main body for one k-tile. hasA/maskA/maskB are literals at call sites.
  auto body = [&](int kt, bool hasA, bool maskA, bool maskB) {
    // stage next tile into other buffer + issue prefetch of tile kt+2
    if (kt + 1 < ntiles) {
      stage_to((kt + 1) & 1);
      if (kt + 2 < ntiles) prefetch();
    }
    const bf16_t* Ks = &KsB[(kt & 1) * BUF];
    const bf16_t* Vt = &VtB[(kt & 1) * BUF];
    bf16x8 kf0s[4], kf1s[4];
    load_kfs(Ks, kf0s, kf1s);
    bf16x8 BpA[2], BpB[2];
    if (hasA) qk_block(kf0s, kf1s, qfA0, qfA1, lAx, BpA, maskA, kt * 64, qgA);
    qk_block(kf0s, kf1s, qfB0, qfB1, lBx, BpB, maskB, kt * 64, qgB);
    bf16x8 A8s[8];
    load_vfs(Vt, A8s);
    __builtin_amdgcn_s_setprio(1);
#pragma unroll
    for (int pr = 0; pr < 2; pr++) {
#pragma unroll
      for (int ct = 0; ct < 4; ct++) {
        if (hasA) oA[ct] = MFMA16(A8s[pr * 4 + ct], BpA[pr], oA[ct]);
        oB[ct] = MFMA16(A8s[pr * 4 + ct], BpB[pr], oB[ct]);
      }
    }
    __builtin_amdgcn_s_setprio(0);
    if (kt + 1 < ntiles) __syncthreads();
  };

  // prologue: tile 0 into buf0, prefetch tile 1, sync
  stage_to(0);
  if (ntiles > 1) prefetch();
  __syncthreads();

  // peeled phases: [0,p) AB | p A-diag | (p,31-p) B-only | 31-p B-diag
  for (int kt = 0; kt < p; kt++) body(kt, true, false, false);
  body(p, true, true, false);
  for (int kt = p + 1; kt < 31 - p; kt++) body(kt, false, false, false);
  body(31 - p, false, false, true);

  // l: sum partials across the 4 quads (k-direction), then normalize+store
  lAx += __shfl_xor(lAx, 16);
  lAx += __shfl_xor(lAx, 32);
  lBx += __shfl_xor(lBx, 16);
  lBx += __shfl_xor(lBx, 32);
  const float invA = __builtin_amdgcn_rcpf(lAx);
  const float invB = __builtin_amdgcn_rcpf(lBx);
  const int ocol = h * 64 + quad * 4;
#pragma unroll
  for (int ct = 0; ct < 4; ct++) {
    bf16x4 wa, wb;
#pragma unroll
    for (int r = 0; r < 4; r++) {
      wa[r] = (bf16_t)(oA[ct][r] * invA);
      wb[r] = (bf16_t)(oB[ct][r] * invB);
    }
    *(bf16x4*)&out[(size_t)(b * 2048 + qgA) * 1024 + ocol + ct * 16] = wa;
    *(bf16x4*)&out[(size_t)(b * 2048 + qgB) * 1024 + ocol + ct * 16] = wb;
  }
}

extern "C" void kernel_launch(void* const* d_in, const int* in_sizes, int n_in,
                              void* d_out, int out_size, void* d_ws, size_t ws_size,
                              hipStream_t stream) {
  const float* x     = (const float*)d_in[0];  // [2,2048,1024]
  const float* w_qkv = (const float*)d_in[1];  // [3072,1024]
  const float* b_qkv = (const float*)d_in[2];  // [3072]
  const float* w_o   = (const float*)d_in[3];  // [1024,1024]
  const float* b_o   = (const float*)d_in[4];  // [1024]
  float* out = (float*)d_out;                  // [2,2048,1024]

  // workspace (bf16): qkv | xbf/attn (aliased) | wqkv_bf | wo_bf  = 42 MB
  bf16_t* qkv   = (bf16_t*)d_ws;
  bf16_t* xbf   = qkv + (size_t)4096 * 3072;
  bf16_t* wqkvb = xbf + (size_t)4096 * 1024;
  bf16_t* wob   = wqkvb + (size_t)3072 * 1024;
  bf16_t* attn  = xbf;  // x dead after GEMM1

  const int na = 4096 * 1024, nb = 3072 * 1024, nc = 1024 * 1024;
  convert3_f32_bf16<<<dim3((na + nb + nc) / (256 * 8)), 256, 0, stream>>>(
      x, na, w_qkv, nb, w_o, nc, xbf, wqkvb, wob);

  // 1) qkv = x @ w_qkv^T + b_qkv   (256^2 8-phase, 12x16 = 192 blocks)
  gemm256_bt_bias<<<dim3(3072 / 256, 4096 / 256), 512, 0, stream>>>(
      xbf, wqkvb, b_qkv, qkv, 4096, 3072, 1024);
  // 2) causal attention, paired q-tiles (p, 31-p): EXACTLY 512 blocks
  attn_kernel<<<dim3(512), 256, 0, stream>>>(qkv, attn);
  // 3) out = attn @ w_o^T + b_o    (128x128 tiles -> 256 blocks)
  gemm_bt_bias<float, 128><<<dim3(1024 / 128, 4096 / 128), 256, 0, stream>>>(
      attn, wob, b_o, out, 4096, 1024, 1024);
}

// Round 6
// 173.042 us; speedup vs baseline: 1.0442x; 1.0442x over previous
//
#include <hip/hip_runtime.h>
#include <hip/hip_bf16.h>
#include <math.h>

typedef __bf16 bf16_t;
typedef __bf16 bf16x8 __attribute__((ext_vector_type(8)));
typedef __bf16 bf16x4 __attribute__((ext_vector_type(4)));
typedef __bf16 bf16x2 __attribute__((ext_vector_type(2)));
typedef float f32x4 __attribute__((ext_vector_type(4)));
typedef unsigned u32x4 __attribute__((ext_vector_type(4)));

// scale 1/sqrt(1024) folded with log2(e), plus half-ulp rounding bias
// (x * 2^0.0028169 = x * (1+2^-9)) so perm-truncation rounds on average.
#define SCALE_L2E 0.045084234f
#define ROUND_B 0.0028169f

#define MFMA16(a, b, c) __builtin_amdgcn_mfma_f32_16x16x32_bf16(a, b, c, 0, 0, 0)

// pack two f32 into bf16x2 (truncate): dst = (hi16(b) << 16) | hi16(a)
__device__ __forceinline__ unsigned pack2(float a, float b) {
  return __builtin_amdgcn_perm(__builtin_bit_cast(unsigned, b),
                               __builtin_bit_cast(unsigned, a), 0x07060302u);
}

// ---------------------------------------------------------------------------
// fused f32 -> bf16 convert of three buffers (x, w_qkv, w_o), 8 elems/thread
// ---------------------------------------------------------------------------
__global__ void convert3_f32_bf16(const float* __restrict__ a, int na,
                                  const float* __restrict__ b, int nb,
                                  const float* __restrict__ c, int nc,
                                  bf16_t* __restrict__ oa, bf16_t* __restrict__ ob,
                                  bf16_t* __restrict__ oc) {
  int i = (blockIdx.x * blockDim.x + threadIdx.x) * 8;
  const float* src;
  bf16_t* dst;
  int off;
  if (i < na) { src = a; dst = oa; off = i; }
  else if (i < na + nb) { src = b; dst = ob; off = i - na; }
  else if (i < na + nb + nc) { src = c; dst = oc; off = i - na - nb; }
  else return;
  float4 u = *(const float4*)&src[off];
  float4 v = *(const float4*)&src[off + 4];
  bf16x8 w = {(bf16_t)u.x, (bf16_t)u.y, (bf16_t)u.z, (bf16_t)u.w,
              (bf16_t)v.x, (bf16_t)v.y, (bf16_t)v.z, (bf16_t)v.w};
  *(bf16x8*)&dst[off] = w;
}

#define GLOBAL_AS __attribute__((address_space(1)))
#define LDS_AS __attribute__((address_space(3)))
__device__ __forceinline__ void g2l16(const void* g, void* l) {
  __builtin_amdgcn_global_load_lds((const GLOBAL_AS void*)g, (LDS_AS void*)l,
                                   16, 0, 0);
}

// ---------------------------------------------------------------------------
// m97-style BT-GEMM, bf16 in: C[m,n] = sum_k A[m,k]*B[n,k] + bias[n]
// GEMM2 uses BN=64 / 512 blocks (2 blocks/CU): R5 measured BN=128 (256
// blocks, 1/CU) at -5.2us — the 2-barrier drain needs a co-resident block
// to overlap with; co-residency >= 2 dominates tile shape here.
// ---------------------------------------------------------------------------
template <typename TC, int BN>
__launch_bounds__(256)
__global__ void gemm_bt_bias(const bf16_t* __restrict__ A,
                             const bf16_t* __restrict__ B,
                             const float* __restrict__ bias,
                             TC* __restrict__ C,
                             int M, int N, int K) {
  constexpr int NT = BN / 32;  // n-frags per wave
  __shared__ bf16_t As[128 * 32];
  __shared__ bf16_t Bs[BN * 32];

  const int t = threadIdx.x;
  const int wave = t >> 6, lane = t & 63, quad = lane >> 4, ln = lane & 15;
  const int wm = (wave >> 1) * 64, wn = (wave & 1) * (BN / 2);
  const int m0 = blockIdx.y * 128, n0 = blockIdx.x * BN;

  const int srow = lane >> 2;
  const int schunk = ((lane & 3) ^ ((lane >> 3) & 3)) * 8;
  const bf16_t* gA0 = &A[(size_t)(m0 + wave * 32 + srow) * K + schunk];
  const bf16_t* gA1 = gA0 + (size_t)16 * K;
  bf16_t* lA0 = &As[(wave * 32) * 32];
  bf16_t* lA1 = &As[(wave * 32 + 16) * 32];
  const bf16_t* gB0 = &B[(size_t)(n0 + (BN == 128 ? wave * 32 : wave * 16) + srow) * K + schunk];
  const bf16_t* gB1 = gB0 + (size_t)16 * K;
  bf16_t* lB0 = &Bs[((BN == 128 ? wave * 32 : wave * 16)) * 32];
  bf16_t* lB1 = &Bs[(wave * 32 + 16) * 32];

  const int cslot = (quad ^ ((ln >> 1) & 3)) * 8;

  f32x4 acc[4][NT];
  for (int i = 0; i < 4; i++)
    for (int j = 0; j < NT; j++) acc[i][j] = (f32x4){0.f, 0.f, 0.f, 0.f};

  for (int k0 = 0; k0 < K; k0 += 32) {
    __syncthreads();
    g2l16(gA0 + k0, lA0);
    g2l16(gA1 + k0, lA1);
    g2l16(gB0 + k0, lB0);
    if (BN == 128) g2l16(gB1 + k0, lB1);
    __syncthreads();

    bf16x8 af[4], bfr[NT];
    for (int mt = 0; mt < 4; mt++)
      af[mt] = *(const bf16x8*)&As[(wm + mt * 16 + ln) * 32 + cslot];
    for (int nt = 0; nt < NT; nt++)
      bfr[nt] = *(const bf16x8*)&Bs[(wn + nt * 16 + ln) * 32 + cslot];
    for (int mt = 0; mt < 4; mt++)
      for (int nt = 0; nt < NT; nt++)
        acc[mt][nt] = MFMA16(af[mt], bfr[nt], acc[mt][nt]);
  }

  for (int nt = 0; nt < NT; nt++) {
    int col = n0 + wn + nt * 16 + ln;
    float bv = bias[col];
    for (int mt = 0; mt < 4; mt++) {
      int row = m0 + wm + mt * 16 + quad * 4;
      for (int r = 0; r < 4; r++)
        C[(size_t)(row + r) * N + col] = (TC)(acc[mt][nt][r] + bv);
    }
  }
}

// ---------------------------------------------------------------------------
// 256x256 8-phase BT-GEMM (T2 swizzle + T3/T4 counted vmcnt + T5 setprio).
// 8 waves (2M x 4N), BK=64, 128 KiB LDS double-buffer. Per K-tile: 4 phases,
// each {ds_read frags | stage one 16KB chunk | barrier | lgkmcnt(0) |
// setprio(1) 16xMFMA setprio(0) | barrier}; vmcnt(4) once per tile.
// Chunk schedule (tile t phases): P1: A_1(t+1)  P2: B_1(t+1)
//                                 P3: A_0(t+2)  P4: B_0(t+2)
// Release proof: A_0 (rows 0-127) last read P2 (mh0); B_0 last read P3 (nh0);
// A_1/B_1 of buf[(t+1)&1] last read P3/P4 of tile t-1. All stage targets are
// disjoint from same-phase reads; vmcnt(4) leaves exactly the 2 newest chunks
// (tile t+2's A_0,B_0) in flight, so tile t+1 is fully landed at its P1.
// Wave ownership interleaved so every chunk is a contiguous 128-row block:
//   wm owns rows {wm*64+[0,64)} u {128+wm*64+[0,64)}
//   wn owns cols {wn*32+[0,32)} u {128+wn*32+[0,32)}
// LDS XOR swizzle: chunk' = chunk ^ (row&7)  (2-way ds_read_b128 -> free);
// global source pre-applies the same involution (rule 21).
// ---------------------------------------------------------------------------
__launch_bounds__(512, 2)
__global__ void gemm256_bt_bias(const bf16_t* __restrict__ A,
                                const bf16_t* __restrict__ B,
                                const float* __restrict__ bias,
                                bf16_t* __restrict__ C,
                                int M, int N, int K) {
  __shared__ __align__(16) bf16_t Ab[2][256 * 64];
  __shared__ __align__(16) bf16_t Bb[2][256 * 64];

  const int tid = threadIdx.x;
  const int wave = tid >> 6, lane = tid & 63, quad = lane >> 4, ln = lane & 15;
  const int wm = wave >> 2, wn = wave & 3;  // 2M x 4N
  const int m0 = blockIdx.y * 256, n0 = blockIdx.x * 256;
  const int nt = K >> 6;

  // staging geometry: wave w stages 8 rows per load, lane l -> row +l/8,
  // stored k-chunk l&7 holds logical chunk (l&7)^(l>>3)  (row&7 == l>>3)
  const int rowoff = wave * 8 + (lane >> 3);
  const int c8 = ((lane & 7) ^ (lane >> 3)) * 8;
  const int w8row = wave * 8;
  const bf16_t* Arow0 = A + (size_t)(m0 + rowoff) * K + c8;
  const bf16_t* Brow0 = B + (size_t)(n0 + rowoff) * K + c8;

  auto stA = [&](int tl, int h) {
    const bf16_t* g = Arow0 + (size_t)(h * 128) * K + (size_t)tl * 64;
    bf16_t* l = &Ab[tl & 1][(h * 128 + w8row) * 64];
    g2l16(g, l);
    g2l16(g + (size_t)64 * K, l + 64 * 64);
  };
  auto stB = [&](int tl, int h) {
    const bf16_t* g = Brow0 + (size_t)(h * 128) * K + (size_t)tl * 64;
    bf16_t* l = &Bb[tl & 1][(h * 128 + w8row) * 64];
    g2l16(g, l);
    g2l16(g + (size_t)64 * K, l + 64 * 64);
  };

  // fragment read addressing (read-side swizzle = same involution)
  const int cswl = (quad ^ (ln & 7)) * 8;     // chunk slot bytes/2 for sk=0
  const int aBase = (wm * 64 + ln) * 64;
  const int bBase = (wn * 32 + ln) * 64;

  f32x4 acc[8][4];
#pragma unroll
  for (int i = 0; i < 8; i++)
#pragma unroll
    for (int j = 0; j < 4; j++) acc[i][j] = (f32x4){0.f, 0.f, 0.f, 0.f};

  bf16x8 af[4][2], bfr[2][2];

  auto ldA4 = [&](int buf, int mh) {
#pragma unroll
    for (int mf = 0; mf < 4; ++mf)
#pragma unroll
      for (int sk = 0; sk < 2; ++sk)
        af[mf][sk] = *(const bf16x8*)&Ab[buf][mh * 8192 + aBase + mf * 1024 +
                                             (cswl ^ (sk << 5))];
  };
  auto ldB2 = [&](int buf, int nh) {
#pragma unroll
    for (int nf = 0; nf < 2; ++nf)
#pragma unroll
      for (int sk = 0; sk < 2; ++sk)
        bfr[nf][sk] = *(const bf16x8*)&Bb[buf][nh * 8192 + bBase + nf * 1024 +
                                               (cswl ^ (sk << 5))];
  };
  auto mm8 = [&](int mh, int nh) {
#pragma unroll
    for (int mf = 0; mf < 4; ++mf)
#pragma unroll
      for (int nf = 0; nf < 2; ++nf) {
        f32x4 c = acc[mh * 4 + mf][nh * 2 + nf];
        c = MFMA16(af[mf][0], bfr[nf][0], c);
        c = MFMA16(af[mf][1], bfr[nf][1], c);
        acc[mh * 4 + mf][nh * 2 + nf] = c;
      }
  };

#define PHASE_MM(MH, NH)                             \
  __builtin_amdgcn_s_barrier();                      \
  asm volatile("s_waitcnt lgkmcnt(0)" ::: "memory"); \
  __builtin_amdgcn_s_setprio(1);                     \
  mm8(MH, NH);                                       \
  __builtin_amdgcn_s_setprio(0);

  // prologue: tile 0 fully + tile 1's A_0,B_0; allow the newest 2 chunks to
  // stay in flight.
  stA(0, 0); stB(0, 0); stA(0, 1); stB(0, 1);
  if (nt > 1) {
    stA(1, 0); stB(1, 0);
    asm volatile("s_waitcnt vmcnt(4)" ::: "memory");
  } else {
    asm volatile("s_waitcnt vmcnt(0)" ::: "memory");
  }
  __builtin_amdgcn_s_barrier();

  for (int tl = 0; tl < nt; ++tl) {
    const int buf = tl & 1;
    // P1 (mh0, nh0)
    ldA4(buf, 0);
    ldB2(buf, 0);
    if (tl + 1 < nt) stA(tl + 1, 1);
    PHASE_MM(0, 0)
    __builtin_amdgcn_s_barrier();
    // P2 (mh0, nh1)
    ldB2(buf, 1);
    if (tl + 1 < nt) stB(tl + 1, 1);
    PHASE_MM(0, 1)
    __builtin_amdgcn_s_barrier();
    // P3 (mh1, nh0)
    ldA4(buf, 1);
    ldB2(buf, 0);
    if (tl + 2 < nt) stA(tl + 2, 0);
    PHASE_MM(1, 0)
    __builtin_amdgcn_s_barrier();
    // P4 (mh1, nh1)
    ldB2(buf, 1);
    if (tl + 2 < nt) stB(tl + 2, 0);
    PHASE_MM(1, 1)
    asm volatile("s_waitcnt vmcnt(4)" ::: "memory");
    __builtin_amdgcn_s_barrier();
  }
#undef PHASE_MM

#pragma unroll
  for (int nf4 = 0; nf4 < 4; ++nf4) {
    const int col = n0 + (nf4 >> 1) * 128 + wn * 32 + (nf4 & 1) * 16 + ln;
    const float bv = bias[col];
#pragma unroll
    for (int mf8 = 0; mf8 < 8; ++mf8) {
      const int row = m0 + (mf8 >> 2) * 128 + wm * 64 + (mf8 & 3) * 16 + quad * 4;
#pragma unroll
      for (int r = 0; r < 4; ++r)
        C[(size_t)(row + r) * N + col] = (bf16_t)(acc[mf8][nf4][r] + bv);
    }
  }
}

// ---------------------------------------------------------------------------
// Causal attention: MFMA layout chaining, fused-pair K=32 PV, DOUBLE-BUFFERED
// LDS (1 barrier/iter) and PEELED causal phases (mask ops only on the 2
// diagonal iterations). Block = paired q-tiles (p, 31-p): 512 blocks, equal
// work, 2/CU co-resident. Paired = best measured (R3 175.5): each staged K/V
// tile and each kf/vf fragment serves TWO q-sets (R4 unpair was neutral).
// R3 XCD-locality: p in HIGH bits, bh in LOW 5 bits -> same-bh -> same XCD
// (mod 8); 4 bh x 512KB K/V = 2MB < 4MB L2/XCD. T5 setprio on MFMA clusters.
// R6: softmax denominator accumulated as f32x4 per-r partial sums (4
// independent dep chains of depth 4/tile, was one 16-deep serial f32 chain).
// GRID MUST BE 512 (1024 clobbers wob via phantom b=2,3 — R4 failure).
// ---------------------------------------------------------------------------
__launch_bounds__(256, 2)
__global__ void attn_kernel(const bf16_t* __restrict__ qkv,
                            bf16_t* __restrict__ out) {
  constexpr int KP = 72, VP = 72;
  constexpr int BUF = 64 * KP;  // elems per K (or V) buffer
  __shared__ __align__(16) bf16_t KsB[2 * BUF];  // [buf][k][d], swizzled
  __shared__ __align__(16) bf16_t VtB[2 * BUF];  // [buf][d][k], swizzled

  const int t = threadIdx.x;
  const int wave = t >> 6, lane = t & 63, quad = lane >> 4, ln = lane & 15;
  const int p = blockIdx.x >> 5;   // pair: q-tiles p and 31-p (0..15)
  const int bh = blockIdx.x & 31;  // 0..31; same-bh -> same XCD (mod-8)
  const int b = bh >> 4, h = bh & 15;
  const int qA = p * 64, qB = (31 - p) * 64;
  const int ntiles = 32 - p;       // A active for kt <= p; B for all
  const size_t rs = 3072;
  const size_t base = (size_t)b * 2048 * rs;

  // Q as B-operand frags: B[d=quad*8+j][q=ln] = Q[q][d]
  const size_t qoffA = base + (size_t)(qA + wave * 16 + ln) * rs + h * 64;
  const size_t qoffB = base + (size_t)(qB + wave * 16 + ln) * rs + h * 64;
  bf16x8 qfA0 = *(const bf16x8*)&qkv[qoffA + quad * 8];
  bf16x8 qfA1 = *(const bf16x8*)&qkv[qoffA + 32 + quad * 8];
  bf16x8 qfB0 = *(const bf16x8*)&qkv[qoffB + quad * 8];
  bf16x8 qfB1 = *(const bf16x8*)&qkv[qoffB + 32 + quad * 8];

  // O^T accumulators: rows d = ct*16+quad*4+r, col q = ln
  f32x4 oA[4], oB[4];
  f32x4 lAv = (f32x4){0.f, 0.f, 0.f, 0.f};
  f32x4 lBv = (f32x4){0.f, 0.f, 0.f, 0.f};
  for (int ct = 0; ct < 4; ct++) {
    oA[ct] = (f32x4){0.f, 0.f, 0.f, 0.f};
    oB[ct] = (f32x4){0.f, 0.f, 0.f, 0.f};
  }

  // staging maps: K rows r0, r0+32 (b128); V rows 2*r0, 2*r0+1 (b32 pairs)
  const int r0 = t >> 3, c0 = (t & 7) * 8;
  const int ksA = r0 * KP + (((t & 7) + wave) & 7) * 8;  // r0>>3 == wave
  const int ksB2 = (r0 + 32) * KP + (((t & 7) + wave + 4) & 7) * 8;
  const int vkoff = ((((r0 >> 2) + (t & 7)) & 7)) * 8 + 2 * (r0 & 3);

  // running global prefetch pointers (advance by 64 rows per tile)
  const bf16_t* kpa = &qkv[base + 1024 + h * 64 + (size_t)r0 * rs + c0];
  const bf16_t* kpb = kpa + (size_t)32 * rs;
  const bf16_t* vpa = &qkv[base + 2048 + h * 64 + (size_t)(2 * r0) * rs + c0];
  const bf16_t* vpb = vpa + rs;
  const size_t tstep = (size_t)64 * rs;

  // tile 0 into regs
  bf16x8 ka = *(const bf16x8*)kpa; kpa += tstep;
  bf16x8 kb = *(const bf16x8*)kpb; kpb += tstep;
  bf16x8 va2 = *(const bf16x8*)vpa; vpa += tstep;
  bf16x8 vb2 = *(const bf16x8*)vpb; vpb += tstep;

  const int qgA = qA + wave * 16 + ln;  // lane's q (S^T column), set A
  const int qgB = qB + wave * 16 + ln;

  // ---- helpers (forceinline lambdas; bool args are literal at call sites)
  auto stage_to = [&](int buf) {
    bf16_t* KsW = &KsB[buf * BUF];
    bf16_t* VtW = &VtB[buf * BUF];
    *(bf16x8*)&KsW[ksA] = ka;
    *(bf16x8*)&KsW[ksB2] = kb;
#pragma unroll
    for (int j = 0; j < 8; j++) {
      bf16x2 w2 = {va2[j], vb2[j]};
      *(bf16x2*)&VtW[(c0 + j) * VP + vkoff] = w2;
    }
  };
  auto prefetch = [&]() {
    ka = *(const bf16x8*)kpa; kpa += tstep;
    kb = *(const bf16x8*)kpb; kpb += tstep;
    va2 = *(const bf16x8*)vpa; vpa += tstep;
    vb2 = *(const bf16x8*)vpb; vpb += tstep;
  };
  auto load_kfs = [&](const bf16_t* Ks, bf16x8* kf0s, bf16x8* kf1s) {
#pragma unroll
    for (int st = 0; st < 4; st++) {
      const int krow = st * 16 + ln;
      const int rot = 2 * st + (ln >> 3);
      kf0s[st] = *(const bf16x8*)&Ks[krow * KP + ((quad + rot) & 7) * 8];
      kf1s[st] = *(const bf16x8*)&Ks[krow * KP + ((quad + 4 + rot) & 7) * 8];
    }
  };
  auto qk_block = [&](const bf16x8* kf0s, const bf16x8* kf1s, bf16x8 q0,
                      bf16x8 q1, f32x4& lxv, bf16x8* Bp, bool masked,
                      int kbase, int qg) {
#pragma unroll
    for (int pr = 0; pr < 2; pr++) {
      u32x4 u;
#pragma unroll
      for (int sh = 0; sh < 2; sh++) {
        const int st = pr * 2 + sh;
        f32x4 s = (f32x4){0.f, 0.f, 0.f, 0.f};
        __builtin_amdgcn_s_setprio(1);
        s = MFMA16(kf0s[st], q0, s);
        s = MFMA16(kf1s[st], q1, s);
        __builtin_amdgcn_s_setprio(0);
        const int k0g = kbase + st * 16 + quad * 4;
        float pv[4];
#pragma unroll
        for (int r = 0; r < 4; r++) {
          float e = __builtin_amdgcn_exp2f(fmaf(s[r], SCALE_L2E, ROUND_B));
          if (masked && (k0g + r > qg)) e = 0.f;
          lxv[r] += e;  // 4 independent chains (was one 16-deep serial chain)
          pv[r] = e;
        }
        u[sh * 2] = pack2(pv[0], pv[1]);
        u[sh * 2 + 1] = pack2(pv[2], pv[3]);
      }
      Bp[pr] = __builtin_bit_cast(bf16x8, u);
    }
  };
  auto load_vfs = [&](const bf16_t* Vt, bf16x8* A8s) {
#pragma unroll
    for (int pr = 0; pr < 2; pr++) {
#pragma unroll
      for (int ct = 0; ct < 4; ct++) {
        const int dd = ct * 16 + ln;
        const int bc = (quad >> 1) + 2 * ct + (ln >> 3);
        const int cA = (4 * pr + bc) & 7;
        const int cB = (4 * pr + 2 + bc) & 7;
        bf16x4 v0 = *(const bf16x4*)&Vt[dd * VP + cA * 8 + (quad & 1) * 4];
        bf16x4 v1 = *(const bf16x4*)&Vt[dd * VP + cB * 8 + (quad & 1) * 4];
        A8s[pr * 4 + ct] = __builtin_shufflevector(v0, v1, 0, 1, 2, 3, 4, 5, 6, 7);
      }
    }
  };

  // main body for one k-tile. hasA/maskA/maskB are literals at call sites.
  auto body = [&](int kt, bool hasA, bool maskA, bool maskB) {
    // stage next tile into other buffer + issue prefetch of tile kt+2
    if (kt + 1 < ntiles) {
      stage_to((kt + 1) & 1);
      if (kt + 2 < ntiles) prefetch();
    }
    const bf16_t* Ks = &KsB[(kt & 1) * BUF];
    const bf16_t* Vt = &VtB[(kt & 1) * BUF];
    bf16x8 kf0s[4], kf1s[4];
    load_kfs(Ks, kf0s, kf1s);
    bf16x8 BpA[2], BpB[2];
    if (hasA) qk_block(kf0s, kf1s, qfA0, qfA1, lAv, BpA, maskA, kt * 64, qgA);
    qk_block(kf0s, kf1s, qfB0, qfB1, lBv, BpB, maskB, kt * 64, qgB);
    bf16x8 A8s[8];
    load_vfs(Vt, A8s);
    __builtin_amdgcn_s_setprio(1);
#pragma unroll
    for (int pr = 0; pr < 2; pr++) {
#pragma unroll
      for (int ct = 0; ct < 4; ct++) {
        if (hasA) oA[ct] = MFMA16(A8s[pr * 4 + ct], BpA[pr], oA[ct]);
        oB[ct] = MFMA16(A8s[pr * 4 + ct], BpB[pr], oB[ct]);
      }
    }
    __builtin_amdgcn_s_setprio(0);
    if (kt + 1 < ntiles) __syncthreads();
  };

  // prologue: tile 0 into buf0, prefetch tile 1, sync
  stage_to(0);
  if (ntiles > 1) prefetch();
  __syncthreads();

  // peeled phases: [0,p) AB | p A-diag | (p,31-p) B-only | 31-p B-diag
  for (int kt = 0; kt < p; kt++) body(kt, true, false, false);
  body(p, true, true, false);
  for (int kt = p + 1; kt < 31 - p; kt++) body(kt, false, false, false);
  body(31 - p, false, false, true);

  // l: fold f32x4 partials, sum across the 4 quads, normalize+store
  float lAx = (lAv[0] + lAv[1]) + (lAv[2] + lAv[3]);
  float lBx = (lBv[0] + lBv[1]) + (lBv[2] + lBv[3]);
  lAx += __shfl_xor(lAx, 16);
  lAx += __shfl_xor(lAx, 32);
  lBx += __shfl_xor(lBx, 16);
  lBx += __shfl_xor(lBx, 32);
  const float invA = __builtin_amdgcn_rcpf(lAx);
  const float invB = __builtin_amdgcn_rcpf(lBx);
  const int ocol = h * 64 + quad * 4;
#pragma unroll
  for (int ct = 0; ct < 4; ct++) {
    bf16x4 wa, wb;
#pragma unroll
    for (int r = 0; r < 4; r++) {
      wa[r] = (bf16_t)(oA[ct][r] * invA);
      wb[r] = (bf16_t)(oB[ct][r] * invB);
    }
    *(bf16x4*)&out[(size_t)(b * 2048 + qgA) * 1024 + ocol + ct * 16] = wa;
    *(bf16x4*)&out[(size_t)(b * 2048 + qgB) * 1024 + ocol + ct * 16] = wb;
  }
}

extern "C" void kernel_launch(void* const* d_in, const int* in_sizes, int n_in,
                              void* d_out, int out_size, void* d_ws, size_t ws_size,
                              hipStream_t stream) {
  const float* x     = (const float*)d_in[0];  // [2,2048,1024]
  const float* w_qkv = (const float*)d_in[1];  // [3072,1024]
  const float* b_qkv = (const float*)d_in[2];  // [3072]
  const float* w_o   = (const float*)d_in[3];  // [1024,1024]
  const float* b_o   = (const float*)d_in[4];  // [1024]
  float* out = (float*)d_out;                  // [2,2048,1024]

  // workspace (bf16): qkv | xbf/attn (aliased) | wqkv_bf | wo_bf  = 42 MB
  bf16_t* qkv   = (bf16_t*)d_ws;
  bf16_t* xbf   = qkv + (size_t)4096 * 3072;
  bf16_t* wqkvb = xbf + (size_t)4096 * 1024;
  bf16_t* wob   = wqkvb + (size_t)3072 * 1024;
  bf16_t* attn  = xbf;  // x dead after GEMM1

  const int na = 4096 * 1024, nb = 3072 * 1024, nc = 1024 * 1024;
  convert3_f32_bf16<<<dim3((na + nb + nc) / (256 * 8)), 256, 0, stream>>>(
      x, na, w_qkv, nb, w_o, nc, xbf, wqkvb, wob);

  // 1) qkv = x @ w_qkv^T + b_qkv   (256^2 8-phase, 12x16 = 192 blocks)
  gemm256_bt_bias<<<dim3(3072 / 256, 4096 / 256), 512, 0, stream>>>(
      xbf, wqkvb, b_qkv, qkv, 4096, 3072, 1024);
  // 2) causal attention, paired q-tiles (p, 31-p): EXACTLY 512 blocks
  attn_kernel<<<dim3(512), 256, 0, stream>>>(qkv, attn);
  // 3) out = attn @ w_o^T + b_o    (128x64 tiles -> 512 blocks, 2/CU)
  gemm_bt_bias<float, 64><<<dim3(1024 / 64, 4096 / 128), 256, 0, stream>>>(
      attn, wob, b_o, out, 4096, 1024, 1024);
}